// Round 7
// baseline (578.222 us; speedup 1.0000x reference)
//
#include <hip/hip_runtime.h>
#include <hip/hip_bf16.h>

#define NH 12
constexpr float SCALE = 0.17677669529663687f;  // 1/sqrt(32)

using f32x4  = __attribute__((ext_vector_type(4))) float;
using bf16x8 = __attribute__((ext_vector_type(8))) __bf16;
using u32x4  = __attribute__((ext_vector_type(4))) unsigned;

// ---------------- K0: weight bf16 conversion + bias table [12][64 i][64 j] ----
// biasI[h][i][j]: j>=49 -> -1e30 (mask padded keys), i>=49 -> 0 (don't care).
__global__ __launch_bounds__(256) void wa_prep(
    const float* __restrict__ qkv_w, const float* __restrict__ proj_w,
    const float* __restrict__ tbl,
    __bf16* __restrict__ qkv_w_bf, __bf16* __restrict__ proj_w_bf,
    float* __restrict__ biasI) {
  int p = blockIdx.x * 256 + threadIdx.x;
  if (p < 442368) { qkv_w_bf[p] = (__bf16)qkv_w[p]; return; }
  p -= 442368;
  if (p < 147456) { proj_w_bf[p] = (__bf16)proj_w[p]; return; }
  p -= 147456;
  if (p >= 49152) return;
  int h = p >> 12, rem = p & 4095, i = rem >> 6, j = rem & 63;
  float v;
  if (j >= 49) v = -1e30f;
  else if (i >= 49) v = 0.0f;
  else {
    int py = i / 7, px = i % 7, qy = j / 7, qx = j % 7;
    v = tbl[((py - qy + 6) * 13 + (px - qx + 6)) * NH + h];
  }
  biasI[p] = v;
}

__device__ inline unsigned pk_bf16(float a, float b) {
  unsigned r;
  asm("v_cvt_pk_bf16_f32 %0, %1, %2" : "=v"(r) : "v"(a), "v"(b));
  return r;  // lo16 = bf16(a), hi16 = bf16(b)
}

// half-exchange (packed): C-frag pair (rows 0-15 in lo, 16-31 in hi; lane holds
// col=lr, rows 4*ls+r) -> operand frag (lane holds its col's k-rows 8ls..8ls+7).
__device__ inline bf16x8 half_ex(f32x4 lo, f32x4 hi, int baA, int baB, bool sel) {
  int l01 = (int)pk_bf16(lo[0], lo[1]), l23 = (int)pk_bf16(lo[2], lo[3]);
  int h01 = (int)pk_bf16(hi[0], hi[1]), h23 = (int)pk_bf16(hi[2], hi[3]);
  int w0a = __builtin_amdgcn_ds_bpermute(baA, l01);
  int w0b = __builtin_amdgcn_ds_bpermute(baA, h01);
  int w1a = __builtin_amdgcn_ds_bpermute(baA, l23);
  int w1b = __builtin_amdgcn_ds_bpermute(baA, h23);
  int w2a = __builtin_amdgcn_ds_bpermute(baB, l01);
  int w2b = __builtin_amdgcn_ds_bpermute(baB, h01);
  int w3a = __builtin_amdgcn_ds_bpermute(baB, l23);
  int w3b = __builtin_amdgcn_ds_bpermute(baB, h23);
  u32x4 w;
  w[0] = (unsigned)(sel ? w0b : w0a);
  w[1] = (unsigned)(sel ? w1b : w1a);
  w[2] = (unsigned)(sel ? w2b : w2a);
  w[3] = (unsigned)(sel ? w3b : w3a);
  return __builtin_bit_cast(bf16x8, w);
}

#define MFMA(a, b, c) __builtin_amdgcn_mfma_f32_16x16x32_bf16(a, b, c, 0, 0, 0)

// ---------------- fused: qkv GEMM + attention + proj, 1 block = 1 window ------
// 4 waves; wave wv owns heads {wv, wv+4, wv+8}. Register-pressure-bounded
// phase schedule (round-6 spilled ~200MB/way at the 128-VGPR heuristic cap):
// A1) K-loop Q^T only -> qb     A2) K-loop K^T only -> ka
// B/C) S^T, bias+exp, row sums, pb
// D) K-loop V   E) PV^T   F) normalize -> Hs
// Then 1 barrier + proj in TWO 48-col passes (acc[4][3] each).
// launch_bounds(256,1): LDS (75KB) caps occupancy at 2 blocks/CU anyway, so
// let regalloc use >128 VGPRs instead of spilling.
__global__ __launch_bounds__(256, 1) void wa_fused(
    const float* __restrict__ x, const __bf16* __restrict__ wqkv,
    const float* __restrict__ qkv_b, const __bf16* __restrict__ wp,
    const float* __restrict__ proj_b, const float* __restrict__ biasI,
    float* __restrict__ out) {
  __shared__ __bf16 As[49 * 384];   // 36.75KB x-tile, chunk^(row&7) swizzle
  __shared__ __bf16 Hs[49 * 384];   // 36.75KB head-output tile, same swizzle
  const int t = threadIdx.x, lane = t & 63, wv = t >> 6;
  const int lr = lane & 15, ls = lane >> 4;
  const int w = blockIdx.x, w49 = w * 49;
  const int srcA = (lane & 15) | ((lane & 16) << 1);
  const int baA = srcA << 2, baB = (srcA + 16) << 2;
  const bool sel = (lane & 32) != 0;
  const f32x4 zero = {0.f, 0.f, 0.f, 0.f};

  // stage x -> As (fp32 -> bf16)
  for (int p = t; p < 2352; p += 256) {
    int row = p / 48, c = p - row * 48;
    const float* src = x + (size_t)(w49 + row) * 384 + c * 8;
    float4 a = *(const float4*)src;
    float4 b = *(const float4*)(src + 4);
    bf16x8 o;
    o[0] = (__bf16)a.x; o[1] = (__bf16)a.y; o[2] = (__bf16)a.z; o[3] = (__bf16)a.w;
    o[4] = (__bf16)b.x; o[5] = (__bf16)b.y; o[6] = (__bf16)b.z; o[7] = (__bf16)b.w;
    int cw = (c & ~7) | ((c & 7) ^ (row & 7));
    *(bf16x8*)(As + row * 384 + cw * 8) = o;
  }
  __syncthreads();

  // xa fragment loader (lane = token, k-chunk c = ks*4+ls)
  auto load_xa = [&](int ks, bf16x8* xa) {
    #pragma unroll
    for (int nt = 0; nt < 4; ++nt) {
      int tok = nt * 16 + lr; if (tok > 48) tok = 48;
      int c = ks * 4 + ls;
      int cw = (c & ~7) | ((c & 7) ^ (tok & 7));
      xa[nt] = *(const bf16x8*)(As + tok * 384 + cw * 8);
    }
  };

  // one W @ x^T pass (result rows = d, cols = tok), wrow = row offset in wqkv
  auto wxT_pass = [&](int wrow, int h, bf16x8* dst) {
    f32x4 cc[2][4] = {};
    for (int ks = 0; ks < 12; ++ks) {
      bf16x8 xa[4];
      load_xa(ks, xa);
      bf16x8 wf[2];
      #pragma unroll
      for (int mt = 0; mt < 2; ++mt) {
        int d = wrow + h * 32 + mt * 16 + lr;
        wf[mt] = *(const bf16x8*)(wqkv + (size_t)d * 384 + (size_t)ks * 32 + ls * 8);
      }
      #pragma unroll
      for (int mt = 0; mt < 2; ++mt)
        #pragma unroll
        for (int nt = 0; nt < 4; ++nt)
          cc[mt][nt] = MFMA(wf[mt], xa[nt], cc[mt][nt]);
    }
    #pragma unroll
    for (int mt = 0; mt < 2; ++mt) {  // rows = d = 16mt + 4ls + r
      float4 bq = *(const float4*)(qkv_b + wrow + h * 32 + mt * 16 + ls * 4);
      #pragma unroll
      for (int nt = 0; nt < 4; ++nt)
        #pragma unroll
        for (int r = 0; r < 4; ++r) cc[mt][nt][r] += ((const float*)&bq)[r];
    }
    #pragma unroll
    for (int nt = 0; nt < 4; ++nt)
      dst[nt] = half_ex(cc[0][nt], cc[1][nt], baA, baB, sel);
  };

  for (int hi = 0; hi < 3; ++hi) {
    const int h = wv + hi * 4;
    // ---- Phase A1/A2: Q^T then K^T (separate passes: ~80-reg peak each)
    bf16x8 qb[4], ka[4];
    wxT_pass(0, h, qb);
    wxT_pass(384, h, ka);
    // ---- Phase B/C: S^T = K @ Q^T; bias + exp; f32 row sums; pack pb
    bf16x8 pb[2][4];
    float s[4] = {0.f, 0.f, 0.f, 0.f};
    {
      f32x4 st[4][4];
      #pragma unroll
      for (int mt = 0; mt < 4; ++mt)
        #pragma unroll
        for (int nt = 0; nt < 4; ++nt)
          st[mt][nt] = MFMA(ka[mt], qb[nt], zero);
      #pragma unroll
      for (int mt = 0; mt < 4; ++mt)
        #pragma unroll
        for (int nt = 0; nt < 4; ++nt) {
          int i = nt * 16 + lr;
          float4 bi = *(const float4*)(biasI + ((size_t)h * 64 + i) * 64 + mt * 16 + ls * 4);
          #pragma unroll
          for (int r = 0; r < 4; ++r) {
            float e = __expf(fmaf(st[mt][nt][r], SCALE, ((const float*)&bi)[r]));
            st[mt][nt][r] = e;
            s[nt] += e;
          }
        }
      #pragma unroll
      for (int nt = 0; nt < 4; ++nt) {
        s[nt] += __shfl_xor(s[nt], 16, 64);
        s[nt] += __shfl_xor(s[nt], 32, 64);
      }
      #pragma unroll
      for (int k2 = 0; k2 < 2; ++k2)
        #pragma unroll
        for (int nt = 0; nt < 4; ++nt)
          pb[k2][nt] = half_ex(st[2 * k2][nt], st[2 * k2 + 1][nt], baA, baB, sel);
    }
    // ---- Phase D: V = x @ Wv^T (rows tok, cols d)
    f32x4 ot[2][4] = {};
    {
      f32x4 cv[4][2] = {};
      for (int ks = 0; ks < 12; ++ks) {
        bf16x8 xa[4];
        load_xa(ks, xa);
        bf16x8 wvb[2];
        #pragma unroll
        for (int nt = 0; nt < 2; ++nt) {
          int d = h * 32 + nt * 16 + lr;
          wvb[nt] = *(const bf16x8*)(wqkv + (size_t)(768 + d) * 384 + (size_t)ks * 32 + ls * 8);
        }
        #pragma unroll
        for (int mt = 0; mt < 4; ++mt)
          #pragma unroll
          for (int nt = 0; nt < 2; ++nt)
            cv[mt][nt] = MFMA(xa[mt], wvb[nt], cv[mt][nt]);
      }
      #pragma unroll
      for (int nt = 0; nt < 2; ++nt) {  // cols = d = 16nt + lr
        float bv = qkv_b[768 + h * 32 + nt * 16 + lr];
        #pragma unroll
        for (int mt = 0; mt < 4; ++mt)
          #pragma unroll
          for (int r = 0; r < 4; ++r) cv[mt][nt][r] += bv;
      }
      // ---- Phase E: V^T operand frags (lane = d, k = tok), PV^T
      bf16x8 va[2][2];
      #pragma unroll
      for (int ct = 0; ct < 2; ++ct)
        #pragma unroll
        for (int k2 = 0; k2 < 2; ++k2)
          va[ct][k2] = half_ex(cv[2 * k2][ct], cv[2 * k2 + 1][ct], baA, baB, sel);
      #pragma unroll
      for (int k2 = 0; k2 < 2; ++k2)
        #pragma unroll
        for (int ct = 0; ct < 2; ++ct)
          #pragma unroll
          for (int nt = 0; nt < 4; ++nt)
            ot[ct][nt] = MFMA(va[ct][k2], pb[k2][nt], ot[ct][nt]);
    }
    // ---- Phase F: normalize, convert H^T -> proj-A layout, write Hs
    #pragma unroll
    for (int nt = 0; nt < 4; ++nt) {
      float inv = 1.0f / s[nt];
      f32x4 h0, h1;
      #pragma unroll
      for (int r = 0; r < 4; ++r) { h0[r] = ot[0][nt][r] * inv; h1[r] = ot[1][nt][r] * inv; }
      bf16x8 pa = half_ex(h0, h1, baA, baB, sel);
      int i = nt * 16 + lr;
      if (i < 49) {
        int c = h * 4 + ls;
        int cw = (c & ~7) | ((c & 7) ^ (i & 7));
        *(bf16x8*)(Hs + i * 384 + cw * 8) = pa;
      }
    }
  }
  __syncthreads();  // Hs complete (all heads, all waves)

  // ---- proj in TWO 48-col passes: out[:, wv*96+half*48 ..+47] = Hs@Wp^T + b
  #pragma unroll 1
  for (int half = 0; half < 2; ++half) {
    f32x4 acc[4][3] = {};
    for (int ks = 0; ks < 12; ++ks) {
      bf16x8 ha[4], wb[3];
      #pragma unroll
      for (int it = 0; it < 4; ++it) {
        int tok = it * 16 + lr; if (tok > 48) tok = 48;
        int c = ks * 4 + ls;
        int cw = (c & ~7) | ((c & 7) ^ (tok & 7));
        ha[it] = *(const bf16x8*)(Hs + tok * 384 + cw * 8);
      }
      #pragma unroll
      for (int ct = 0; ct < 3; ++ct) {
        int n = wv * 96 + half * 48 + ct * 16 + lr;
        wb[ct] = *(const bf16x8*)(wp + (size_t)n * 384 + ks * 32 + ls * 8);
      }
      #pragma unroll
      for (int it = 0; it < 4; ++it)
        #pragma unroll
        for (int ct = 0; ct < 3; ++ct)
          acc[it][ct] = MFMA(ha[it], wb[ct], acc[it][ct]);
    }
    float pbias[3];
    #pragma unroll
    for (int ct = 0; ct < 3; ++ct) pbias[ct] = proj_b[wv * 96 + half * 48 + ct * 16 + lr];
    #pragma unroll
    for (int it = 0; it < 4; ++it)
      #pragma unroll
      for (int r = 0; r < 4; ++r) {
        int i = it * 16 + ls * 4 + r;
        if (i < 49) {
          float* dst = out + (size_t)(w49 + i) * 384 + wv * 96 + half * 48;
          #pragma unroll
          for (int ct = 0; ct < 3; ++ct)
            dst[ct * 16 + lr] = acc[it][ct][r] + pbias[ct];
        }
      }
  }
}

extern "C" void kernel_launch(void* const* d_in, const int* in_sizes, int n_in,
                              void* d_out, int out_size, void* d_ws, size_t ws_size,
                              hipStream_t stream) {
  const float* x      = (const float*)d_in[0];
  const float* qkv_w  = (const float*)d_in[1];
  const float* qkv_b  = (const float*)d_in[2];
  const float* proj_w = (const float*)d_in[3];
  const float* proj_b = (const float*)d_in[4];
  const float* tbl    = (const float*)d_in[5];
  float* out = (float*)d_out;

  char* ws = (char*)d_ws;
  __bf16* qkv_w_bf  = (__bf16*)ws;                  // 884,736 B
  __bf16* proj_w_bf = (__bf16*)(ws + 884736);       // 294,912 B
  float*  biasI     = (float*)(ws + 1179648);       // 196,608 B

  wa_prep<<<2496, 256, 0, stream>>>(qkv_w, proj_w, tbl, qkv_w_bf, proj_w_bf, biasI);
  wa_fused<<<2048, 256, 0, stream>>>(x, qkv_w_bf, qkv_b, proj_w_bf, proj_b, biasI, out);
}

// Round 8
// 336.483 us; speedup vs baseline: 1.7184x; 1.7184x over previous
//
#include <hip/hip_runtime.h>
#include <hip/hip_bf16.h>

#define NH 12
constexpr float SCALE = 0.17677669529663687f;  // 1/sqrt(32)
constexpr int TOKENS = 100352;

using f32x4  = __attribute__((ext_vector_type(4))) float;
using bf16x8 = __attribute__((ext_vector_type(8))) __bf16;

__device__ inline void gload_lds16(const void* g, void* l) {
  __builtin_amdgcn_global_load_lds(
      (const __attribute__((address_space(1))) void*)g,
      (__attribute__((address_space(3))) void*)l, 16, 0, 0);
}

__device__ inline bf16x8 cvt8(float4 a, float4 b) {
  bf16x8 o;
  o[0] = (__bf16)a.x; o[1] = (__bf16)a.y; o[2] = (__bf16)a.z; o[3] = (__bf16)a.w;
  o[4] = (__bf16)b.x; o[5] = (__bf16)b.y; o[6] = (__bf16)b.z; o[7] = (__bf16)b.w;
  return o;
}

#define MFMA(a, b, c) __builtin_amdgcn_mfma_f32_16x16x32_bf16(a, b, c, 0, 0, 0)

// ---------------- K0: weight bf16 conversion + transposed padded bias ----------
// biasTt layout: [12][64 col(j)][64 row(i)] fp32; j>=49 -> -1e30 (mask), i>=49 -> 0.
__global__ __launch_bounds__(256) void wa_prep(
    const float* __restrict__ qkv_w, const float* __restrict__ proj_w,
    const float* __restrict__ tbl,
    __bf16* __restrict__ qkv_w_bf, __bf16* __restrict__ proj_w_bf,
    float* __restrict__ biasTt) {
  int p = blockIdx.x * 256 + threadIdx.x;
  if (p < 442368) { qkv_w_bf[p] = (__bf16)qkv_w[p]; return; }
  p -= 442368;
  if (p < 147456) { proj_w_bf[p] = (__bf16)proj_w[p]; return; }
  p -= 147456;
  if (p >= 49152) return;
  int h = p >> 12, rem = p & 4095, j = rem >> 6, i = rem & 63;  // j=key col, i=query row
  float v;
  if (j >= 49) v = -1e30f;
  else if (i >= 49) v = 0.0f;
  else {
    int py = i / 7, px = i % 7, qy = j / 7, qx = j % 7;
    v = tbl[((py - qy + 6) * 13 + (px - qx + 6)) * NH + h];
  }
  biasTt[p] = v;
}

// ---------------- K1: QKV GEMM 64x128, BK=64, high-occupancy ----------------
// 4 blocks/CU (40KB LDS, VGPR<=128). Grid 14112 XCD-grouped: the 9 nb-blocks
// of one mb land on one XCD (x HBM-read once, L2 re-reads). 2 barriers/step,
// TLP (16 waves/CU) hides stage latency (m114 implicit overlap).
__global__ __launch_bounds__(256, 4) void wa_qkv(
    const float* __restrict__ x, const __bf16* __restrict__ wq,
    const float* __restrict__ qkv_b, __bf16* __restrict__ qkv) {
  __shared__ __bf16 As[64 * 64];    // 8KB  [row][chunk ^ (row&7)]
  __shared__ __bf16 Bs[128 * 64];   // 16KB [col][chunk ^ (col&7)] linear dest
  __shared__ __bf16 Cs[64 * 128];   // 16KB epilogue roundtrip
  const int t = threadIdx.x, lane = t & 63, wv = t >> 6;
  const int lr = lane & 15, ls = lane >> 4;
  const int bid = blockIdx.x;
  const int q = bid / 72, rem = bid - q * 72;
  const int nb = rem >> 3, mb = q * 8 + (rem & 7);
  const int wr = wv >> 1, wc = wv & 1;   // wave tile: 32 rows x 64 cols
  f32x4 acc[2][4] = {};
  for (int kk = 0; kk < 6; ++kk) {
    if (kk) __syncthreads();
    // issue A fp32 loads (2 chunks/thread) + B gload_lds (4/thread)
    float4 a0[2], a1[2];
    int rowA[2], cA[2];
    #pragma unroll
    for (int j = 0; j < 2; ++j) {
      int p = j * 256 + t;
      rowA[j] = p >> 3; cA[j] = p & 7;
      const float* src = x + (size_t)(mb * 64 + rowA[j]) * 384 + kk * 64 + cA[j] * 8;
      a0[j] = *(const float4*)src;
      a1[j] = *(const float4*)(src + 4);
    }
    #pragma unroll
    for (int j = 0; j < 4; ++j) {
      int p = j * 256 + t;
      int c = p >> 3, sl = p & 7;
      gload_lds16(wq + (size_t)(nb * 128 + c) * 384 + kk * 64 + (sl ^ (c & 7)) * 8,
                  Bs + p * 8);
    }
    #pragma unroll
    for (int j = 0; j < 2; ++j) {
      int cw = cA[j] ^ (rowA[j] & 7);
      *(bf16x8*)(As + rowA[j] * 64 + cw * 8) = cvt8(a0[j], a1[j]);
    }
    __syncthreads();
    #pragma unroll
    for (int ks = 0; ks < 2; ++ks) {
      bf16x8 af[2], bfr[4];
      #pragma unroll
      for (int rt = 0; rt < 2; ++rt) {
        int row = wr * 32 + rt * 16 + lr;
        af[rt] = *(const bf16x8*)(As + row * 64 + (((ks * 4 + ls) ^ (row & 7)) * 8));
      }
      #pragma unroll
      for (int ct = 0; ct < 4; ++ct) {
        int c = wc * 64 + ct * 16 + lr;
        bfr[ct] = *(const bf16x8*)(Bs + c * 64 + (((ks * 4 + ls) ^ (c & 7)) * 8));
      }
      #pragma unroll
      for (int rt = 0; rt < 2; ++rt)
        #pragma unroll
        for (int ct = 0; ct < 4; ++ct)
          acc[rt][ct] = MFMA(af[rt], bfr[ct], acc[rt][ct]);
    }
  }
  // epilogue: + bias -> Cs -> coalesced bf16x8 stores
  #pragma unroll
  for (int ct = 0; ct < 4; ++ct) {
    float b = qkv_b[nb * 128 + wc * 64 + ct * 16 + lr];
    #pragma unroll
    for (int rt = 0; rt < 2; ++rt)
      #pragma unroll
      for (int r = 0; r < 4; ++r) {
        int row = wr * 32 + rt * 16 + ls * 4 + r;
        Cs[row * 128 + wc * 64 + ct * 16 + lr] = (__bf16)(acc[rt][ct][r] + b);
      }
  }
  __syncthreads();
  #pragma unroll
  for (int j = 0; j < 4; ++j) {
    int p = j * 256 + t;
    int row = p >> 4, sub = p & 15;
    *(bf16x8*)(qkv + (size_t)(mb * 64 + row) * 1152 + nb * 128 + sub * 8) =
        *(const bf16x8*)(Cs + p * 8);
  }
}

// ---------------- K2a: attention, one wave per (window, head) ----------------
// 24576 independent waves, no barriers. V staged in wave-private LDS (vector
// loads, chunk-XOR swizzle). Softmax: no max-sub (bounded), denom via ones-MFMA.
// H written into the Q-slice of qkv (owned by this (w,h)).
__global__ __launch_bounds__(256, 3) void wa_attn(
    const float* __restrict__ biasTt, __bf16* __restrict__ qkv) {
  __shared__ __bf16 Pbuf[4][4096];  // 8KB/wave
  __shared__ __bf16 Vbuf[4][2048];  // 4KB/wave
  const int t = threadIdx.x, lane = t & 63, wv = t >> 6;
  const int lr = lane & 15, ls = lane >> 4;
  const int pair = blockIdx.x * 4 + wv;     // 0..24575
  const int w = pair / NH, h = pair - w * NH;
  const int w49 = w * 49;
  __bf16* Pw = Pbuf[wv];
  __bf16* Vw = Vbuf[wv];
  f32x4 zero = {0.f, 0.f, 0.f, 0.f};
  bf16x8 ones;
  #pragma unroll
  for (int e = 0; e < 8; ++e) ones[e] = (__bf16)1.0f;

  // stage V: lane = row j (rows>=49 clamp to 48: finite, killed by P=0)
  {
    int row = lane;
    int tok = w49 + (row < 49 ? row : 48);
    const bf16x8* vsrc = (const bf16x8*)(qkv + (size_t)tok * 1152 + 768 + h * 32);
    int f = (row & 3) ^ ((row >> 3) & 3);
    #pragma unroll
    for (int c = 0; c < 4; ++c)
      *(bf16x8*)(Vw + row * 32 + ((c ^ f) * 8)) = vsrc[c];
  }
  // Q,K fragments direct from global (full 64B lines per 16 rows)
  bf16x8 qa[4], kb[4];
  #pragma unroll
  for (int rt = 0; rt < 4; ++rt) {
    int tok = min(w49 + rt * 16 + lr, TOKENS - 1);
    qa[rt] = *(const bf16x8*)(qkv + (size_t)tok * 1152 + h * 32 + ls * 8);
  }
  #pragma unroll
  for (int ct = 0; ct < 4; ++ct) {
    int tok = min(w49 + ct * 16 + lr, TOKENS - 1);
    kb[ct] = *(const bf16x8*)(qkv + (size_t)tok * 1152 + 384 + h * 32 + ls * 8);
  }
  f32x4 sacc[4][4];
  #pragma unroll
  for (int rt = 0; rt < 4; ++rt)
    #pragma unroll
    for (int ct = 0; ct < 4; ++ct)
      sacc[rt][ct] = MFMA(qa[rt], kb[ct], zero);
  // scale + bias + exp -> swizzled Pbuf (unnormalized probs; masked cols -> 0)
  #pragma unroll
  for (int rt = 0; rt < 4; ++rt) {
    int row0 = rt * 16 + ls * 4;
    #pragma unroll
    for (int ct = 0; ct < 4; ++ct) {
      int col = ct * 16 + lr;
      float4 bias = *(const float4*)(biasTt + (size_t)(h * 64 + col) * 64 + row0);
      #pragma unroll
      for (int r = 0; r < 4; ++r) {
        int row = row0 + r;
        float pr = __expf(fmaf(sacc[rt][ct][r], SCALE, ((const float*)&bias)[r]));
        Pw[row * 64 + (((col >> 3) ^ (row & 7)) * 8) + (col & 7)] = (__bf16)pr;
      }
    }
  }
  // PV + row sums (ones trick); V^T frags from LDS (swizzled scalar reads)
  f32x4 oacc[4][2] = {};
  f32x4 osum[4] = {zero, zero, zero, zero};
  #pragma unroll
  for (int ks = 0; ks < 2; ++ks) {
    bf16x8 vb0, vb1;
    #pragma unroll
    for (int e = 0; e < 8; ++e) {
      int j = ks * 32 + ls * 8 + e;
      int a = j * 32 + (((lr >> 3) ^ (e & 3) ^ ls) * 8) + (lr & 7);
      vb0[e] = Vw[a];
      vb1[e] = Vw[a ^ 16];
    }
    #pragma unroll
    for (int rt = 0; rt < 4; ++rt) {
      int row = rt * 16 + lr;
      bf16x8 pa = *(const bf16x8*)(Pw + row * 64 + (((ks * 4 + ls) ^ (row & 7)) * 8));
      oacc[rt][0] = MFMA(pa, vb0, oacc[rt][0]);
      oacc[rt][1] = MFMA(pa, vb1, oacc[rt][1]);
      osum[rt]    = MFMA(pa, ones, osum[rt]);
    }
  }
  // normalize + write H into Q slice (rows < 49 only)
  #pragma unroll
  for (int rt = 0; rt < 4; ++rt)
    #pragma unroll
    for (int r = 0; r < 4; ++r) {
      int row = rt * 16 + ls * 4 + r;
      if (row < 49) {
        float inv = 1.0f / osum[rt][r];
        __bf16* o = qkv + (size_t)(w49 + row) * 1152 + h * 32;
        o[lr]      = (__bf16)(oacc[rt][0][r] * inv);
        o[16 + lr] = (__bf16)(oacc[rt][1][r] * inv);
      }
    }
}

// ---------------- K2b: proj GEMM 64x128, BK=64, high-occupancy ----------------
// A = H (bf16, qkv cols 0..383) via gload_lds; 24KB LDS -> LDS no limit,
// VGPR<=128 -> 4+ blocks/CU. Grid 4704 XCD-grouped (3 nb-blocks per mb).
__global__ __launch_bounds__(256, 4) void wa_proj(
    const __bf16* __restrict__ qkv, const __bf16* __restrict__ pw,
    const float* __restrict__ proj_b, float* __restrict__ out) {
  __shared__ __bf16 As[64 * 64];    // 8KB
  __shared__ __bf16 Bs[128 * 64];   // 16KB
  const int t = threadIdx.x, lane = t & 63, wv = t >> 6;
  const int lr = lane & 15, ls = lane >> 4;
  const int bid = blockIdx.x;
  const int q = bid / 24, rem = bid - q * 24;
  const int nb = rem >> 3, mb = q * 8 + (rem & 7);
  const int wr = wv >> 1, wc = wv & 1;
  f32x4 acc[2][4] = {};
  for (int kk = 0; kk < 6; ++kk) {
    if (kk) __syncthreads();
    #pragma unroll
    for (int j = 0; j < 2; ++j) {  // A tile via gload_lds, source pre-swizzled
      int p = j * 256 + t;
      int row = p >> 3, sl = p & 7;
      gload_lds16(qkv + (size_t)(mb * 64 + row) * 1152 + kk * 64 + (sl ^ (row & 7)) * 8,
                  As + p * 8);
    }
    #pragma unroll
    for (int j = 0; j < 4; ++j) {
      int p = j * 256 + t;
      int c = p >> 3, sl = p & 7;
      gload_lds16(pw + (size_t)(nb * 128 + c) * 384 + kk * 64 + (sl ^ (c & 7)) * 8,
                  Bs + p * 8);
    }
    __syncthreads();
    #pragma unroll
    for (int ks = 0; ks < 2; ++ks) {
      bf16x8 af[2], bfr[4];
      #pragma unroll
      for (int rt = 0; rt < 2; ++rt) {
        int row = wr * 32 + rt * 16 + lr;
        af[rt] = *(const bf16x8*)(As + row * 64 + (((ks * 4 + ls) ^ (row & 7)) * 8));
      }
      #pragma unroll
      for (int ct = 0; ct < 4; ++ct) {
        int c = wc * 64 + ct * 16 + lr;
        bfr[ct] = *(const bf16x8*)(Bs + c * 64 + (((ks * 4 + ls) ^ (c & 7)) * 8));
      }
      #pragma unroll
      for (int rt = 0; rt < 2; ++rt)
        #pragma unroll
        for (int ct = 0; ct < 4; ++ct)
          acc[rt][ct] = MFMA(af[rt], bfr[ct], acc[rt][ct]);
    }
  }
  // epilogue: fp32 direct stores (16-lane 64B runs) + bias
  #pragma unroll
  for (int ct = 0; ct < 4; ++ct) {
    int col = nb * 128 + wc * 64 + ct * 16 + lr;
    float b = proj_b[col];
    #pragma unroll
    for (int rt = 0; rt < 2; ++rt)
      #pragma unroll
      for (int r = 0; r < 4; ++r) {
        int row = wr * 32 + rt * 16 + ls * 4 + r;
        out[(size_t)(mb * 64 + row) * 384 + col] = acc[rt][ct][r] + b;
      }
  }
}

extern "C" void kernel_launch(void* const* d_in, const int* in_sizes, int n_in,
                              void* d_out, int out_size, void* d_ws, size_t ws_size,
                              hipStream_t stream) {
  const float* x      = (const float*)d_in[0];
  const float* qkv_w  = (const float*)d_in[1];
  const float* qkv_b  = (const float*)d_in[2];
  const float* proj_w = (const float*)d_in[3];
  const float* proj_b = (const float*)d_in[4];
  const float* tbl    = (const float*)d_in[5];
  float* out = (float*)d_out;

  char* ws = (char*)d_ws;
  __bf16* qkv_w_bf  = (__bf16*)ws;                  // 884,736 B
  __bf16* proj_w_bf = (__bf16*)(ws + 884736);       // 294,912 B
  float*  biasTt    = (float*)(ws + 1179648);       // 196,608 B
  __bf16* qkv_buf   = (__bf16*)(ws + 1376256);      // 231,211,008 B

  wa_prep<<<2496, 256, 0, stream>>>(qkv_w, proj_w, tbl, qkv_w_bf, proj_w_bf, biasTt);
  wa_qkv<<<14112, 256, 0, stream>>>(x, qkv_w_bf, qkv_b, qkv_buf);
  wa_attn<<<6144, 256, 0, stream>>>(biasTt, qkv_buf);
  wa_proj<<<4704, 256, 0, stream>>>(qkv_buf, proj_w_bf, proj_b, out);
}